// Round 6
// baseline (500.535 us; speedup 1.0000x reference)
//
#include <hip/hip_runtime.h>
#include <hip/hip_bf16.h>

#define HID    1024
#define NBATCH 32
#define SRC    2048
#define MROWS  (NBATCH * SRC)   // 65536

typedef _Float16 f16;
typedef f16   f16x8 __attribute__((ext_vector_type(8)));
typedef f16   f16x4 __attribute__((ext_vector_type(4)));
typedef float f32x4 __attribute__((ext_vector_type(4)));

#define BAR()    __builtin_amdgcn_s_barrier()
#define SCHED0() __builtin_amdgcn_sched_barrier(0)

__device__ __forceinline__ void gload_lds16(const void* g, void* l) {
  __builtin_amdgcn_global_load_lds(
      (const __attribute__((address_space(1))) void*)g,
      (__attribute__((address_space(3))) void*)l, 16, 0, 0);
}

__device__ __forceinline__ float fast_tanh(float x) {
  x = fminf(fmaxf(x, -15.f), 15.f);
  float e = __expf(2.f * x);
  return (e - 1.f) / (e + 1.f);
}

// ---------------------------------------------------------------- kernel 1
__global__ void convw_k(const float* __restrict__ attn_w, f16* __restrict__ Wf) {
  int idx = blockIdx.x * 256 + threadIdx.x;
  int j = idx * 4;
  int o = j >> 10, h = j & 1023;
  f32x4 d = *(const f32x4*)(attn_w + (size_t)o * 2048 + HID + h);
  f16x4 q = { (f16)d[0], (f16)d[1], (f16)d[2], (f16)d[3] };
  *(f16x4*)(Wf + (size_t)o * HID + h) = q;
}

// ---------------------------------------------------------------- kernel 2
__global__ void hvec_k(const float* __restrict__ hidden,
                       const float* __restrict__ attn_w,
                       const float* __restrict__ attn_b,
                       float* __restrict__ hvec) {
  int idx = blockIdx.x * 256 + threadIdx.x;
  int b = idx >> 10, o = idx & 1023;
  const float* wrow = attn_w + (size_t)o * 2048;
  const float* hrow = hidden + (size_t)b * HID;
  float acc = 0.f;
  for (int h = 0; h < HID; h += 4) {
    f32x4 wv = *(const f32x4*)(wrow + h);
    f32x4 hv = *(const f32x4*)(hrow + h);
    acc += wv[0]*hv[0] + wv[1]*hv[1] + wv[2]*hv[2] + wv[3]*hv[3];
  }
  hvec[idx] = acc + attn_b[o];
}

// ---------------------------------------------------------------- kernel 2b
__global__ void convA_k(const float* __restrict__ A, f16* __restrict__ Af) {
  size_t i = ((size_t)blockIdx.x * 256 + threadIdx.x) * 8;
  f32x4 d0 = *(const f32x4*)(A + i);
  f32x4 d1 = *(const f32x4*)(A + i + 4);
  f16x8 q = { (f16)d0[0], (f16)d0[1], (f16)d0[2], (f16)d0[3],
              (f16)d1[0], (f16)d1[1], (f16)d1[2], (f16)d1[3] };
  *(f16x8*)(Af + i) = q;
}

// ---------------------------------------------------------------- kernel 3
// BM=256 BN=128 BK=64. 8 waves as 4M x 2N (per-wave 64x64, acc=64 VGPR).
// A: global_load_lds, TRIPLE-buffered (3 x 32 KB), depth-2 DMA prefetch.
// B: direct global->reg fragments (Wf is L2-resident; 8 contig f16/lane),
//    prefetched one K-tile ahead. Counted vmcnt, never 0 in steady state:
//    outstanding = [DMA(T+1):4][B(T):8][DMA(T+2):4] -> vmcnt(4) at P0.
// 4 zigzag phases/K-tile (Q(0,0),(0,1),(1,1),(1,0)); aF reads 1 phase ahead.

#define STG_A3(Tn, bi) do { \
  _Pragma("unroll") for (int q_ = 0; q_ < 4; ++q_) \
    gload_lds16(Ab + (size_t)(q_ * 64 + (tid >> 3)) * HID + (Tn) * 64 + scol, \
                lds + (bi) * 32768 + q_ * 8192 + w * 1024); } while (0)

#define RD_AF(dst, mh_, bi) do { \
  const char* ab_ = lds + (bi) * 32768; \
  _Pragma("unroll") for (int m2 = 0; m2 < 2; ++m2) { \
    const char* rb_ = ab_ + (wr * 64 + (mh_) * 32 + m2 * 16 + lr) * 128; \
    dst[m2][0] = *(const f16x8*)(rb_ + ((lg ^ sw) << 4)); \
    dst[m2][1] = *(const f16x8*)(rb_ + (((4 + lg) ^ sw) << 4)); } } while (0)

#define LD_B8(dst, Tn) do { \
  _Pragma("unroll") for (int nq = 0; nq < 4; ++nq) { \
    const f16* bp_ = Bb + (size_t)(wc * 64 + nq * 16 + lr) * HID + (Tn) * 64 + lg * 8; \
    dst[nq][0] = *(const f16x8*)bp_; \
    dst[nq][1] = *(const f16x8*)(bp_ + 32); } } while (0)

#define MFMA8(af, mh_, nh_, bs) do { \
  __builtin_amdgcn_s_setprio(1); \
  _Pragma("unroll") for (int ks = 0; ks < 2; ++ks) \
  _Pragma("unroll") for (int m2 = 0; m2 < 2; ++m2) \
  _Pragma("unroll") for (int n2 = 0; n2 < 2; ++n2) \
    acc[(mh_)*2+m2][(nh_)*2+n2] = __builtin_amdgcn_mfma_f32_16x16x32_f16( \
        af[m2][ks], bs[(nh_)*2+n2][ks], acc[(mh_)*2+m2][(nh_)*2+n2], 0, 0, 0); \
  __builtin_amdgcn_s_setprio(0); } while (0)

// one K-tile: bC = current B regs, bN = next B regs (filled this tile)
#define TILE(T_, bC, bN, DO2, DOB, DOR, VMN) do { \
  /* P0 */ \
  RD_AF(aFB, 1, (T_) % 3); \
  if (DO2) STG_A3((T_) + 2, ((T_) + 2) % 3); \
  asm volatile("s_waitcnt vmcnt(" #VMN ")" ::: "memory"); \
  SCHED0(); \
  MFMA8(aFA, 0, 0, bC); \
  BAR(); \
  /* P1 */ \
  if (DOB) LD_B8(bN, (T_) + 1); \
  SCHED0(); \
  MFMA8(aFA, 0, 1, bC); \
  BAR(); \
  /* P2 */ \
  MFMA8(aFB, 1, 1, bC); \
  BAR(); \
  /* P3 */ \
  if (DOR) RD_AF(aFA, 0, ((T_) + 1) % 3); \
  MFMA8(aFB, 1, 0, bC); \
  BAR(); \
} while (0)

__global__ __launch_bounds__(512, 2) void gemm_f16(
    const f16*  __restrict__ Af,     // (65536, 1024) f16
    const f16*  __restrict__ Wf,     // (1024, 1024) f16
    const float* __restrict__ hvec,  // (32, 1024)
    const float* __restrict__ v,     // (1024)
    float* __restrict__ part)        // (8, MROWS)
{
  extern __shared__ __align__(16) char lds[];   // 98304 = 3 x 32 KB (A only)

  int bid = blockIdx.x;                   // 2048 blocks
  int wg = (bid & 7) * 256 + (bid >> 3);  // bijective XCD-chunked swizzle
  int m_idx = wg >> 3, n_idx = wg & 7;    // 8 n-blocks share one A panel in XCD L2
  long row0 = (long)m_idx * 256;
  int o0 = n_idx * 128;
  int b = (int)(row0 >> 11);

  int tid = threadIdx.x;
  int l = tid & 63, w = tid >> 6;         // 8 waves
  int wr = w >> 1, wc = w & 1;            // 4 (M) x 2 (N); per-wave 64 x 64
  int lr = l & 15, lg = l >> 4;
  int sw = lr & 7;                        // ds_read-side 16B-slot XOR
  int scol = ((tid & 7) ^ ((tid >> 3) & 7)) * 8;  // pre-swizzled global col (f16)

  const f16* Ab = Af + row0 * HID;
  const f16* Bb = Wf + (size_t)o0 * HID;

  f32x4 acc[4][4];
#pragma unroll
  for (int m = 0; m < 4; ++m)
#pragma unroll
    for (int n = 0; n < 4; ++n) acc[m][n] = (f32x4){0.f, 0.f, 0.f, 0.f};

  f16x8 aFA[2][2], aFB[2][2];
  f16x8 bX[4][2], bY[4][2];

  // ---- prologue: DMA(0), B(0), DMA(1); wait DMA(0) (12 left in flight)
  STG_A3(0, 0);
  LD_B8(bX, 0);
  STG_A3(1, 1);
  asm volatile("s_waitcnt vmcnt(12)" ::: "memory");
  SCHED0();
  BAR();
  RD_AF(aFA, 0, 0);

  // ---- 16 K-tiles, fully unrolled (buf mod 3 x regset mod 2 -> period 6)
  TILE( 0, bX, bY, 1, 1, 1, 4);
  TILE( 1, bY, bX, 1, 1, 1, 4);
  TILE( 2, bX, bY, 1, 1, 1, 4);
  TILE( 3, bY, bX, 1, 1, 1, 4);
  TILE( 4, bX, bY, 1, 1, 1, 4);
  TILE( 5, bY, bX, 1, 1, 1, 4);
  TILE( 6, bX, bY, 1, 1, 1, 4);
  TILE( 7, bY, bX, 1, 1, 1, 4);
  TILE( 8, bX, bY, 1, 1, 1, 4);
  TILE( 9, bY, bX, 1, 1, 1, 4);
  TILE(10, bX, bY, 1, 1, 1, 4);
  TILE(11, bY, bX, 1, 1, 1, 4);
  TILE(12, bX, bY, 1, 1, 1, 4);
  TILE(13, bY, bX, 1, 1, 1, 4);
  TILE(14, bX, bY, 0, 1, 1, 0);   // no DMA(16); conservative drain
  TILE(15, bY, bX, 0, 0, 0, 0);   // last tile: no staging at all

  // ---- fused epilogue: tanh(C + hvec) . v reduced over this block's 128 o's
  float hvv[4], vvv[4];
#pragma unroll
  for (int n = 0; n < 4; ++n) {
    int o = o0 + wc * 64 + n * 16 + lr;
    hvv[n] = hvec[b * HID + o];
    vvv[n] = v[o];
  }
  float* scf = (float*)lds;   // 2 KB scratch, aliases buf0 (dead after sync)
  __syncthreads();
#pragma unroll
  for (int m = 0; m < 4; ++m) {
#pragma unroll
    for (int r = 0; r < 4; ++r) {
      float s = 0.f;
#pragma unroll
      for (int n = 0; n < 4; ++n)
        s += fast_tanh(acc[m][n][r] + hvv[n]) * vvv[n];
      s += __shfl_xor(s, 1); s += __shfl_xor(s, 2);
      s += __shfl_xor(s, 4); s += __shfl_xor(s, 8);
      if (lr == 0) scf[wc * 256 + wr * 64 + m * 16 + lg * 4 + r] = s;
    }
  }
  __syncthreads();
  if (tid < 256)
    part[(size_t)n_idx * MROWS + row0 + tid] = scf[tid] + scf[256 + tid];
}

// ---------------------------------------------------------------- kernel 3 (fallback)
__global__ __launch_bounds__(256, 2) void gemm_fb(
    const float* __restrict__ A, const f16* __restrict__ Wf,
    const float* __restrict__ hvec, const float* __restrict__ v,
    float* __restrict__ part)
{
  __shared__ __align__(16) f16 lA[128][32];
  __shared__ __align__(16) f16 lB[128][32];
  __shared__ float sc[128];

  int bid = blockIdx.x;
  int x = bid & 7, j = bid >> 3;
  int m_idx = x * 64 + (j >> 3);
  int n_idx = j & 7;
  long row0 = (long)m_idx * 128;
  int o0 = n_idx * 128;
  int b = (int)(row0 >> 11);

  int tid = threadIdx.x;
  int l = tid & 63, w = tid >> 6;
  int wr = w >> 1, wc = w & 1;
  int lr = l & 15, lg = l >> 4;

  f32x4 acc[4][4];
#pragma unroll
  for (int m = 0; m < 4; ++m)
#pragma unroll
    for (int n = 0; n < 4; ++n) acc[m][n] = (f32x4){0.f, 0.f, 0.f, 0.f};

  const float* Abase = A + row0 * 1024;

  for (int k0 = 0; k0 < 1024; k0 += 32) {
    __syncthreads();
#pragma unroll
    for (int i = 0; i < 2; ++i) {
      int rr = (i * 256 + tid) >> 2;
      const f16* src = Wf + (size_t)(o0 + rr) * HID + k0 + (tid & 3) * 8;
      char* ldsb = (char*)&lB[0][0] + i * 4096 + w * 1024;
      gload_lds16(src, ldsb);
    }
#pragma unroll
    for (int i = 0; i < 4; ++i) {
      int ja = i * 256 + tid;
      int arow = ja >> 3, ac4 = ja & 7;
      f32x4 d = *(const f32x4*)(Abase + (size_t)arow * 1024 + k0 + ac4 * 4);
      f16x4 q = { (f16)d[0], (f16)d[1], (f16)d[2], (f16)d[3] };
      *(f16x4*)&lA[arow][ac4 * 4] = q;
    }
    __syncthreads();
    f16x8 aF[4], bF[4];
#pragma unroll
    for (int m = 0; m < 4; ++m)
      aF[m] = *(const f16x8*)&lA[wr * 64 + m * 16 + lr][lg * 8];
#pragma unroll
    for (int n = 0; n < 4; ++n)
      bF[n] = *(const f16x8*)&lB[wc * 64 + n * 16 + lr][lg * 8];
#pragma unroll
    for (int m = 0; m < 4; ++m)
#pragma unroll
      for (int n = 0; n < 4; ++n)
        acc[m][n] = __builtin_amdgcn_mfma_f32_16x16x32_f16(aF[m], bF[n], acc[m][n], 0, 0, 0);
  }

  float hv[4], vv[4];
#pragma unroll
  for (int n = 0; n < 4; ++n) {
    int o = o0 + wc * 64 + n * 16 + lr;
    hv[n] = hvec[b * HID + o];
    vv[n] = v[o];
  }
  float myv[4][4];
#pragma unroll
  for (int m = 0; m < 4; ++m) {
#pragma unroll
    for (int r = 0; r < 4; ++r) {
      float s = 0.f;
#pragma unroll
      for (int n = 0; n < 4; ++n)
        s += fast_tanh(acc[m][n][r] + hv[n]) * vv[n];
      s += __shfl_xor(s, 1); s += __shfl_xor(s, 2);
      s += __shfl_xor(s, 4); s += __shfl_xor(s, 8);
      myv[m][r] = s;
    }
  }
  if (wc == 0 && lr == 0) {
#pragma unroll
    for (int m = 0; m < 4; ++m)
#pragma unroll
      for (int r = 0; r < 4; ++r)
        sc[wr * 64 + m * 16 + lg * 4 + r] = myv[m][r];
  }
  __syncthreads();
  if (wc == 1 && lr == 0) {
#pragma unroll
    for (int m = 0; m < 4; ++m)
#pragma unroll
      for (int r = 0; r < 4; ++r)
        sc[wr * 64 + m * 16 + lg * 4 + r] += myv[m][r];
  }
  __syncthreads();
  if (tid < 128)
    part[(size_t)n_idx * MROWS + row0 + tid] = sc[tid];
}

// ---------------------------------------------------------------- kernel 4
__global__ void softmax_k(const float* __restrict__ part, float* __restrict__ out,
                          int nsl) {
  int b = blockIdx.x;
  __shared__ float srow[SRC];
  __shared__ float red[8];
  int tid = threadIdx.x;  // 256

  float lmax = -1e30f;
  for (int i = tid; i < SRC; i += 256) {
    float s = 0.f;
    for (int t = 0; t < nsl; ++t)
      s += part[(size_t)t * MROWS + (size_t)b * SRC + i];
    srow[i] = s;
    lmax = fmaxf(lmax, s);
  }
#pragma unroll
  for (int off = 32; off >= 1; off >>= 1)
    lmax = fmaxf(lmax, __shfl_xor(lmax, off));
  if ((tid & 63) == 0) red[tid >> 6] = lmax;
  __syncthreads();
  float bmax = fmaxf(fmaxf(red[0], red[1]), fmaxf(red[2], red[3]));

  float lsum = 0.f;
  for (int i = tid; i < SRC; i += 256) {
    float e = __expf(srow[i] - bmax);
    srow[i] = e;
    lsum += e;
  }
#pragma unroll
  for (int off = 32; off >= 1; off >>= 1)
    lsum += __shfl_xor(lsum, off);
  if ((tid & 63) == 0) red[4 + (tid >> 6)] = lsum;
  __syncthreads();
  float inv = 1.f / (red[4] + red[5] + red[6] + red[7]);
  for (int i = tid; i < SRC; i += 256)
    out[(size_t)b * SRC + i] = srow[i] * inv;
}

// ---------------------------------------------------------------- launch
extern "C" void kernel_launch(void* const* d_in, const int* in_sizes, int n_in,
                              void* d_out, int out_size, void* d_ws, size_t ws_size,
                              hipStream_t stream) {
  const float* hidden = (const float*)d_in[0];
  const float* enc    = (const float*)d_in[1];
  const float* attn_w = (const float*)d_in[2];
  const float* attn_b = (const float*)d_in[3];
  const float* v      = (const float*)d_in[4];
  float* out = (float*)d_out;

  char* ws = (char*)d_ws;
  f16*   Wf   = (f16*)ws;                                     // 2 MB @ 0
  float* hv   = (float*)(ws + (2ull << 20));                  // 128 KB
  float* part = (float*)(ws + (2ull << 20) + (128ull << 10)); // 2 MB (8 slices)
  f16*   Af   = (f16*)(ws + (8ull << 20));                    // 128 MB

  const size_t WS_NEEDED = (8ull << 20) + (128ull << 20);

  convw_k<<<1024, 256, 0, stream>>>(attn_w, Wf);
  hvec_k <<<128,  256, 0, stream>>>(hidden, attn_w, attn_b, hv);

  if (ws_size >= WS_NEEDED) {
    convA_k<<<32768, 256, 0, stream>>>(enc, Af);
    gemm_f16<<<2048, 512, 98304, stream>>>(Af, Wf, hv, v, part);
    softmax_k<<<NBATCH, 256, 0, stream>>>(part, out, 8);
  } else {
    gemm_fb<<<4096, 256, 0, stream>>>(enc, Wf, hv, v, part);
    softmax_k<<<NBATCH, 256, 0, stream>>>(part, out, 8);
  }
}

// Round 7
// 303.807 us; speedup vs baseline: 1.6475x; 1.6475x over previous
//
#include <hip/hip_runtime.h>
#include <hip/hip_bf16.h>

#define HID    1024
#define NBATCH 32
#define SRC    2048
#define MROWS  (NBATCH * SRC)   // 65536

typedef _Float16 f16;
typedef f16   f16x8 __attribute__((ext_vector_type(8)));
typedef f16   f16x4 __attribute__((ext_vector_type(4)));
typedef float f32x4 __attribute__((ext_vector_type(4)));

#define BAR()    __builtin_amdgcn_s_barrier()
#define SCHED0() __builtin_amdgcn_sched_barrier(0)

__device__ __forceinline__ void gload_lds16(const void* g, void* l) {
  __builtin_amdgcn_global_load_lds(
      (const __attribute__((address_space(1))) void*)g,
      (__attribute__((address_space(3))) void*)l, 16, 0, 0);
}

__device__ __forceinline__ float fast_tanh(float x) {
  x = fminf(fmaxf(x, -15.f), 15.f);
  float e = __expf(2.f * x);
  return (e - 1.f) / (e + 1.f);
}

// ---------------------------------------------------------------- kernel 1
__global__ void convw_k(const float* __restrict__ attn_w, f16* __restrict__ Wf) {
  int idx = blockIdx.x * 256 + threadIdx.x;
  int j = idx * 4;
  int o = j >> 10, h = j & 1023;
  f32x4 d = *(const f32x4*)(attn_w + (size_t)o * 2048 + HID + h);
  f16x4 q = { (f16)d[0], (f16)d[1], (f16)d[2], (f16)d[3] };
  *(f16x4*)(Wf + (size_t)o * HID + h) = q;
}

// ---------------------------------------------------------------- kernel 2
__global__ void hvec_k(const float* __restrict__ hidden,
                       const float* __restrict__ attn_w,
                       const float* __restrict__ attn_b,
                       float* __restrict__ hvec) {
  int idx = blockIdx.x * 256 + threadIdx.x;
  int b = idx >> 10, o = idx & 1023;
  const float* wrow = attn_w + (size_t)o * 2048;
  const float* hrow = hidden + (size_t)b * HID;
  float acc = 0.f;
  for (int h = 0; h < HID; h += 4) {
    f32x4 wv = *(const f32x4*)(wrow + h);
    f32x4 hv = *(const f32x4*)(hrow + h);
    acc += wv[0]*hv[0] + wv[1]*hv[1] + wv[2]*hv[2] + wv[3]*hv[3];
  }
  hvec[idx] = acc + attn_b[o];
}

// ---------------------------------------------------------------- kernel 2b
__global__ void convA_k(const float* __restrict__ A, f16* __restrict__ Af) {
  size_t i = ((size_t)blockIdx.x * 256 + threadIdx.x) * 8;
  f32x4 d0 = *(const f32x4*)(A + i);
  f32x4 d1 = *(const f32x4*)(A + i + 4);
  f16x8 q = { (f16)d0[0], (f16)d0[1], (f16)d0[2], (f16)d0[3],
              (f16)d1[0], (f16)d1[1], (f16)d1[2], (f16)d1[3] };
  *(f16x8*)(Af + i) = q;
}

// ---------------------------------------------------------------- kernel 3
// BM=256 BN=128 BK=64. 8 waves as 4M x 2N (per-wave 64x64, acc=64 VGPR).
// A and B both via global_load_lds, TRIPLE-buffered (3 x 48 KB = 144 KB).
// Full tile T+2 staged (6 gloads spread over tile T's body); boundary is
// vmcnt(6) + ONE s_barrier + sched_barrier(0) per K-tile — no mid-tile
// barriers (triple buffer makes them unnecessary); waves free-run within a
// tile so ds_read of one wave overlaps MFMA of another; setprio biases MFMA.
// XOR swizzle: pre-swizzled global source col + XOR'd ds_read (both-sides).

#define STG_A2(Tn, bs_, h_) do { \
  _Pragma("unroll") for (int q_ = 0; q_ < 2; ++q_) \
    gload_lds16(Ab + (size_t)((h_) * 128 + q_ * 64 + (tid >> 3)) * HID + (Tn) * 64 + scol, \
                lds + (bs_) * 49152 + ((h_) * 2 + q_) * 8192 + w * 1024); } while (0)
#define STG_B2(Tn, bs_) do { \
  _Pragma("unroll") for (int q_ = 0; q_ < 2; ++q_) \
    gload_lds16(Bb + (size_t)(q_ * 64 + (tid >> 3)) * HID + (Tn) * 64 + scol, \
                lds + (bs_) * 49152 + 32768 + q_ * 8192 + w * 1024); } while (0)

#define RD_AF(dst, mh_, bi_) do { \
  const char* ab_ = lds + (bi_) * 49152; \
  _Pragma("unroll") for (int m2 = 0; m2 < 2; ++m2) { \
    const char* rb_ = ab_ + (wr * 64 + (mh_) * 32 + m2 * 16 + lr) * 128; \
    dst[m2][0] = *(const f16x8*)(rb_ + ((lg ^ sw) << 4)); \
    dst[m2][1] = *(const f16x8*)(rb_ + (((4 + lg) ^ sw) << 4)); } } while (0)

#define RD_BF(dst, nh_, bi_) do { \
  const char* bb_ = lds + (bi_) * 49152 + 32768; \
  _Pragma("unroll") for (int n2 = 0; n2 < 2; ++n2) { \
    const char* rb_ = bb_ + (wc * 64 + (nh_) * 32 + n2 * 16 + lr) * 128; \
    dst[n2][0] = *(const f16x8*)(rb_ + ((lg ^ sw) << 4)); \
    dst[n2][1] = *(const f16x8*)(rb_ + (((4 + lg) ^ sw) << 4)); } } while (0)

#define MFMA8(af, bf, mh_, nh_) do { \
  __builtin_amdgcn_s_setprio(1); \
  _Pragma("unroll") for (int ks = 0; ks < 2; ++ks) \
  _Pragma("unroll") for (int m2 = 0; m2 < 2; ++m2) \
  _Pragma("unroll") for (int n2 = 0; n2 < 2; ++n2) \
    acc[(mh_)*2+m2][(nh_)*2+n2] = __builtin_amdgcn_mfma_f32_16x16x32_f16( \
        af[m2][ks], bf[n2][ks], acc[(mh_)*2+m2][(nh_)*2+n2], 0, 0, 0); \
  __builtin_amdgcn_s_setprio(0); } while (0)

// tile body: compute tile from buf bi_, stage tile Tn into buf bs_ (if DOSTG)
#define TILE_BODY(bi_, bs_, Tn, DOSTG) do { \
  RD_AF(aF0, 0, bi_); \
  RD_BF(bF0, 0, bi_); \
  if (DOSTG) STG_A2(Tn, bs_, 0); \
  MFMA8(aF0, bF0, 0, 0); \
  RD_BF(bF1, 1, bi_); \
  if (DOSTG) STG_A2(Tn, bs_, 1); \
  MFMA8(aF0, bF1, 0, 1); \
  RD_AF(aF1, 1, bi_); \
  if (DOSTG) STG_B2(Tn, bs_); \
  MFMA8(aF1, bF1, 1, 1); \
  MFMA8(aF1, bF0, 1, 0); \
} while (0)

__global__ __launch_bounds__(512, 2) void gemm_f16(
    const f16*  __restrict__ Af,     // (65536, 1024) f16
    const f16*  __restrict__ Wf,     // (1024, 1024) f16
    const float* __restrict__ hvec,  // (32, 1024)
    const float* __restrict__ v,     // (1024)
    float* __restrict__ part)        // (8, MROWS)
{
  extern __shared__ __align__(16) char lds[];   // 147456 = 3 x (A 32K + B 16K)

  int bid = blockIdx.x;                   // 2048 blocks
  int wg = (bid & 7) * 256 + (bid >> 3);  // bijective XCD-chunked swizzle
  int m_idx = wg >> 3, n_idx = wg & 7;    // 8 n-blocks share one A panel in XCD L2
  long row0 = (long)m_idx * 256;
  int o0 = n_idx * 128;
  int b = (int)(row0 >> 11);

  int tid = threadIdx.x;
  int l = tid & 63, w = tid >> 6;         // 8 waves
  int wr = w >> 1, wc = w & 1;            // 4 (M) x 2 (N); per-wave 64 x 64
  int lr = l & 15, lg = l >> 4;
  int sw = lr & 7;                        // ds_read-side 16B-slot XOR
  int scol = ((tid & 7) ^ ((tid >> 3) & 7)) * 8;  // pre-swizzled global col (f16)

  const f16* Ab = Af + row0 * HID;
  const f16* Bb = Wf + (size_t)o0 * HID;

  f32x4 acc[4][4];
#pragma unroll
  for (int m = 0; m < 4; ++m)
#pragma unroll
    for (int n = 0; n < 4; ++n) acc[m][n] = (f32x4){0.f, 0.f, 0.f, 0.f};

  f16x8 aF0[2][2], aF1[2][2], bF0[2][2], bF1[2][2];

  // ---- prologue: stage tiles 0 and 1 (12 gloads); wait tile 0 (6 remain)
  STG_A2(0, 0, 0); STG_A2(0, 0, 1); STG_B2(0, 0);
  STG_A2(1, 1, 0); STG_A2(1, 1, 1); STG_B2(1, 1);
  asm volatile("s_waitcnt vmcnt(6)" ::: "memory");
  BAR(); SCHED0();

  // ---- steady state: tiles 0..13 (stage T+2, boundary vmcnt(6))
  int bi = 0, bs = 2;
#pragma unroll 1
  for (int T = 0; T < 14; ++T) {
    TILE_BODY(bi, bs, T + 2, 1);
    asm volatile("s_waitcnt vmcnt(6)" ::: "memory");
    BAR(); SCHED0();
    bi = (bi == 2) ? 0 : bi + 1;
    bs = (bs == 2) ? 0 : bs + 1;
  }
  // ---- tile 14: nothing to stage; drain (tile 15 staged 4+ phases ago)
  TILE_BODY(bi, bs, 0, 0);
  asm volatile("s_waitcnt vmcnt(0)" ::: "memory");
  BAR(); SCHED0();
  bi = (bi == 2) ? 0 : bi + 1;
  // ---- tile 15: last
  TILE_BODY(bi, 0, 0, 0);

  // ---- fused epilogue: tanh(C + hvec) . v reduced over this block's 128 o's
  float hvv[4], vvv[4];
#pragma unroll
  for (int n = 0; n < 4; ++n) {
    int o = o0 + wc * 64 + n * 16 + lr;
    hvv[n] = hvec[b * HID + o];
    vvv[n] = v[o];
  }
  float* scf = (float*)lds;   // 2 KB scratch, aliases buf0 (dead after sync)
  __syncthreads();
#pragma unroll
  for (int m = 0; m < 4; ++m) {
#pragma unroll
    for (int r = 0; r < 4; ++r) {
      float s = 0.f;
#pragma unroll
      for (int n = 0; n < 4; ++n)
        s += fast_tanh(acc[m][n][r] + hvv[n]) * vvv[n];
      s += __shfl_xor(s, 1); s += __shfl_xor(s, 2);
      s += __shfl_xor(s, 4); s += __shfl_xor(s, 8);
      if (lr == 0) scf[wc * 256 + wr * 64 + m * 16 + lg * 4 + r] = s;
    }
  }
  __syncthreads();
  if (tid < 256)
    part[(size_t)n_idx * MROWS + row0 + tid] = scf[tid] + scf[256 + tid];
}

// ---------------------------------------------------------------- kernel 3 (fallback)
__global__ __launch_bounds__(256, 2) void gemm_fb(
    const float* __restrict__ A, const f16* __restrict__ Wf,
    const float* __restrict__ hvec, const float* __restrict__ v,
    float* __restrict__ part)
{
  __shared__ __align__(16) f16 lA[128][32];
  __shared__ __align__(16) f16 lB[128][32];
  __shared__ float sc[128];

  int bid = blockIdx.x;
  int x = bid & 7, j = bid >> 3;
  int m_idx = x * 64 + (j >> 3);
  int n_idx = j & 7;
  long row0 = (long)m_idx * 128;
  int o0 = n_idx * 128;
  int b = (int)(row0 >> 11);

  int tid = threadIdx.x;
  int l = tid & 63, w = tid >> 6;
  int wr = w >> 1, wc = w & 1;
  int lr = l & 15, lg = l >> 4;

  f32x4 acc[4][4];
#pragma unroll
  for (int m = 0; m < 4; ++m)
#pragma unroll
    for (int n = 0; n < 4; ++n) acc[m][n] = (f32x4){0.f, 0.f, 0.f, 0.f};

  const float* Abase = A + row0 * 1024;

  for (int k0 = 0; k0 < 1024; k0 += 32) {
    __syncthreads();
#pragma unroll
    for (int i = 0; i < 2; ++i) {
      int rr = (i * 256 + tid) >> 2;
      const f16* src = Wf + (size_t)(o0 + rr) * HID + k0 + (tid & 3) * 8;
      char* ldsb = (char*)&lB[0][0] + i * 4096 + w * 1024;
      gload_lds16(src, ldsb);
    }
#pragma unroll
    for (int i = 0; i < 4; ++i) {
      int ja = i * 256 + tid;
      int arow = ja >> 3, ac4 = ja & 7;
      f32x4 d = *(const f32x4*)(Abase + (size_t)arow * 1024 + k0 + ac4 * 4);
      f16x4 q = { (f16)d[0], (f16)d[1], (f16)d[2], (f16)d[3] };
      *(f16x4*)&lA[arow][ac4 * 4] = q;
    }
    __syncthreads();
    f16x8 aF[4], bF[4];
#pragma unroll
    for (int m = 0; m < 4; ++m)
      aF[m] = *(const f16x8*)&lA[wr * 64 + m * 16 + lr][lg * 8];
#pragma unroll
    for (int n = 0; n < 4; ++n)
      bF[n] = *(const f16x8*)&lB[wc * 64 + n * 16 + lr][lg * 8];
#pragma unroll
    for (int m = 0; m < 4; ++m)
#pragma unroll
      for (int n = 0; n < 4; ++n)
        acc[m][n] = __builtin_amdgcn_mfma_f32_16x16x32_f16(aF[m], bF[n], acc[m][n], 0, 0, 0);
  }

  float hv[4], vv[4];
#pragma unroll
  for (int n = 0; n < 4; ++n) {
    int o = o0 + wc * 64 + n * 16 + lr;
    hv[n] = hvec[b * HID + o];
    vv[n] = v[o];
  }
  float myv[4][4];
#pragma unroll
  for (int m = 0; m < 4; ++m) {
#pragma unroll
    for (int r = 0; r < 4; ++r) {
      float s = 0.f;
#pragma unroll
      for (int n = 0; n < 4; ++n)
        s += fast_tanh(acc[m][n][r] + hv[n]) * vv[n];
      s += __shfl_xor(s, 1); s += __shfl_xor(s, 2);
      s += __shfl_xor(s, 4); s += __shfl_xor(s, 8);
      myv[m][r] = s;
    }
  }
  if (wc == 0 && lr == 0) {
#pragma unroll
    for (int m = 0; m < 4; ++m)
#pragma unroll
      for (int r = 0; r < 4; ++r)
        sc[wr * 64 + m * 16 + lg * 4 + r] = myv[m][r];
  }
  __syncthreads();
  if (wc == 1 && lr == 0) {
#pragma unroll
    for (int m = 0; m < 4; ++m)
#pragma unroll
      for (int r = 0; r < 4; ++r)
        sc[wr * 64 + m * 16 + lg * 4 + r] += myv[m][r];
  }
  __syncthreads();
  if (tid < 128)
    part[(size_t)n_idx * MROWS + row0 + tid] = sc[tid];
}

// ---------------------------------------------------------------- kernel 4
__global__ void softmax_k(const float* __restrict__ part, float* __restrict__ out,
                          int nsl) {
  int b = blockIdx.x;
  __shared__ float srow[SRC];
  __shared__ float red[8];
  int tid = threadIdx.x;  // 256

  float lmax = -1e30f;
  for (int i = tid; i < SRC; i += 256) {
    float s = 0.f;
    for (int t = 0; t < nsl; ++t)
      s += part[(size_t)t * MROWS + (size_t)b * SRC + i];
    srow[i] = s;
    lmax = fmaxf(lmax, s);
  }
#pragma unroll
  for (int off = 32; off >= 1; off >>= 1)
    lmax = fmaxf(lmax, __shfl_xor(lmax, off));
  if ((tid & 63) == 0) red[tid >> 6] = lmax;
  __syncthreads();
  float bmax = fmaxf(fmaxf(red[0], red[1]), fmaxf(red[2], red[3]));

  float lsum = 0.f;
  for (int i = tid; i < SRC; i += 256) {
    float e = __expf(srow[i] - bmax);
    srow[i] = e;
    lsum += e;
  }
#pragma unroll
  for (int off = 32; off >= 1; off >>= 1)
    lsum += __shfl_xor(lsum, off);
  if ((tid & 63) == 0) red[4 + (tid >> 6)] = lsum;
  __syncthreads();
  float inv = 1.f / (red[4] + red[5] + red[6] + red[7]);
  for (int i = tid; i < SRC; i += 256)
    out[(size_t)b * SRC + i] = srow[i] * inv;
}

// ---------------------------------------------------------------- launch
extern "C" void kernel_launch(void* const* d_in, const int* in_sizes, int n_in,
                              void* d_out, int out_size, void* d_ws, size_t ws_size,
                              hipStream_t stream) {
  const float* hidden = (const float*)d_in[0];
  const float* enc    = (const float*)d_in[1];
  const float* attn_w = (const float*)d_in[2];
  const float* attn_b = (const float*)d_in[3];
  const float* v      = (const float*)d_in[4];
  float* out = (float*)d_out;

  char* ws = (char*)d_ws;
  f16*   Wf   = (f16*)ws;                                     // 2 MB @ 0
  float* hv   = (float*)(ws + (2ull << 20));                  // 128 KB
  float* part = (float*)(ws + (2ull << 20) + (128ull << 10)); // 2 MB (8 slices)
  f16*   Af   = (f16*)(ws + (8ull << 20));                    // 128 MB

  const size_t WS_NEEDED = (8ull << 20) + (128ull << 20);

  convw_k<<<1024, 256, 0, stream>>>(attn_w, Wf);
  hvec_k <<<128,  256, 0, stream>>>(hidden, attn_w, attn_b, hv);

  if (ws_size >= WS_NEEDED) {
    convA_k<<<32768, 256, 0, stream>>>(enc, Af);
    gemm_f16<<<2048, 512, 147456, stream>>>(Af, Wf, hv, v, part);
    softmax_k<<<NBATCH, 256, 0, stream>>>(part, out, 8);
  } else {
    gemm_fb<<<4096, 256, 0, stream>>>(enc, Wf, hv, v, part);
    softmax_k<<<NBATCH, 256, 0, stream>>>(part, out, 8);
  }
}

// Round 8
// 286.470 us; speedup vs baseline: 1.7473x; 1.0605x over previous
//
#include <hip/hip_runtime.h>
#include <hip/hip_bf16.h>

#define HID    1024
#define NBATCH 32
#define SRC    2048
#define MROWS  (NBATCH * SRC)   // 65536

typedef _Float16 f16;
typedef f16   f16x8 __attribute__((ext_vector_type(8)));
typedef f16   f16x4 __attribute__((ext_vector_type(4)));
typedef float f32x4 __attribute__((ext_vector_type(4)));

#define BAR()    __builtin_amdgcn_s_barrier()
#define LGKM0()  asm volatile("s_waitcnt lgkmcnt(0)")
#define SCHED0() __builtin_amdgcn_sched_barrier(0)
#define VMC(n)   asm volatile("s_waitcnt vmcnt(" #n ")")

__device__ __forceinline__ void gload_lds16(const void* g, void* l) {
  __builtin_amdgcn_global_load_lds(
      (const __attribute__((address_space(1))) void*)g,
      (__attribute__((address_space(3))) void*)l, 16, 0, 0);
}

__device__ __forceinline__ float fast_tanh(float x) {
  x = fminf(fmaxf(x, -15.f), 15.f);
  float e = __expf(2.f * x);
  return (e - 1.f) / (e + 1.f);
}

// ---------------------------------------------------------------- kernel 1
__global__ void convw_k(const float* __restrict__ attn_w, f16* __restrict__ Wf) {
  int idx = blockIdx.x * 256 + threadIdx.x;
  int j = idx * 4;
  int o = j >> 10, h = j & 1023;
  f32x4 d = *(const f32x4*)(attn_w + (size_t)o * 2048 + HID + h);
  f16x4 q = { (f16)d[0], (f16)d[1], (f16)d[2], (f16)d[3] };
  *(f16x4*)(Wf + (size_t)o * HID + h) = q;
}

// ---------------------------------------------------------------- kernel 2
__global__ void hvec_k(const float* __restrict__ hidden,
                       const float* __restrict__ attn_w,
                       const float* __restrict__ attn_b,
                       float* __restrict__ hvec) {
  int idx = blockIdx.x * 256 + threadIdx.x;
  int b = idx >> 10, o = idx & 1023;
  const float* wrow = attn_w + (size_t)o * 2048;
  const float* hrow = hidden + (size_t)b * HID;
  float acc = 0.f;
  for (int h = 0; h < HID; h += 4) {
    f32x4 wv = *(const f32x4*)(wrow + h);
    f32x4 hv = *(const f32x4*)(hrow + h);
    acc += wv[0]*hv[0] + wv[1]*hv[1] + wv[2]*hv[2] + wv[3]*hv[3];
  }
  hvec[idx] = acc + attn_b[o];
}

// ---------------------------------------------------------------- kernel 2b
__global__ void convA_k(const float* __restrict__ A, f16* __restrict__ Af) {
  size_t i = ((size_t)blockIdx.x * 256 + threadIdx.x) * 8;
  f32x4 d0 = *(const f32x4*)(A + i);
  f32x4 d1 = *(const f32x4*)(A + i + 4);
  f16x8 q = { (f16)d0[0], (f16)d0[1], (f16)d0[2], (f16)d0[3],
              (f16)d1[0], (f16)d1[1], (f16)d1[2], (f16)d1[3] };
  *(f16x8*)(Af + i) = q;
}

// ---------------------------------------------------------------- kernel 3
// m201-faithful 8-phase schedule at BM=BN=256, BK=64, 8 waves (2M x 4N,
// per-wave 128x64), 128 KB double-buffered LDS (slot = tile parity).
// Per 2-K-tile iteration: 8 phases; each phase = {ds_reads + 2 gload_lds
// stage issues, pinned BEFORE barrier} -> BAR -> lgkmcnt(0) -> setprio(1)
// 16 MFMA setprio(0) -> [vmcnt(2) at phases 4,8 ONLY - never 0] -> BAR.
// Stage ledger (units u0..u7 of 8 KB, A=u0-3, B=u4-7):
//   slot1 tile O=E+1: u0,u1@ph8(prev) u2,u3@ph1 u4,u5@ph2 u6,u7@ph3; read ph5-7
//   slot0 tile E+2  : u0,u1@ph4 u2,u3@ph5 u4,u5@ph6 u6,u7@ph7; read next ph1-3
// vmcnt(2)@ph4: tile O complete (2 newer = E+2's u0,u1). vmcnt(2)@ph8: tile
// E+2 complete (2 newer = E+3's u0,u1). Zigzag quadrants (0,0)(0,1)(1,1)(1,0)
// per tile: fragment reads 12/4/8/0, each fragment read from LDS exactly once.

#define STG1(u, Tn) do { \
  const f16* s_ = ((u) < 4 ? Ab : Bb) + \
      (size_t)(((u) & 3) * 64 + (tid >> 3)) * HID + (Tn) * 64 + scol; \
  char* d_ = lds + ((Tn) & 1) * 65536 + ((u) < 4 ? 0 : 32768) + ((u) & 3) * 8192 + w * 1024; \
  gload_lds16(s_, d_); } while (0)

#define RD_A(la_, mh_) do { \
  _Pragma("unroll") for (int m4 = 0; m4 < 4; ++m4) { \
    const char* rb = (la_) + (wr * 128 + (mh_) * 64 + m4 * 16 + lr) * 128; \
    aF[m4][0] = *(const f16x8*)(rb + ((lg ^ sw) << 4)); \
    aF[m4][1] = *(const f16x8*)(rb + (((4 + lg) ^ sw) << 4)); } } while (0)

#define RD_B(lb_, dst, nh_) do { \
  _Pragma("unroll") for (int n2 = 0; n2 < 2; ++n2) { \
    const char* rb = (lb_) + (wc * 64 + (nh_) * 32 + n2 * 16 + lr) * 128; \
    dst[n2][0] = *(const f16x8*)(rb + ((lg ^ sw) << 4)); \
    dst[n2][1] = *(const f16x8*)(rb + (((4 + lg) ^ sw) << 4)); } } while (0)

#define MFMA16(bsrc, mh_, nh_) do { \
  __builtin_amdgcn_s_setprio(1); \
  _Pragma("unroll") for (int ks = 0; ks < 2; ++ks) \
  _Pragma("unroll") for (int m4 = 0; m4 < 4; ++m4) \
  _Pragma("unroll") for (int n2 = 0; n2 < 2; ++n2) \
    acc[(mh_) * 4 + m4][(nh_) * 2 + n2] = __builtin_amdgcn_mfma_f32_16x16x32_f16( \
        aF[m4][ks], bsrc[n2][ks], acc[(mh_) * 4 + m4][(nh_) * 2 + n2], 0, 0, 0); \
  __builtin_amdgcn_s_setprio(0); } while (0)

__global__ __launch_bounds__(512, 2) void gemm_f16(
    const f16*  __restrict__ Af,     // (65536, 1024) f16
    const f16*  __restrict__ Wf,     // (1024, 1024) f16
    const float* __restrict__ hvec,  // (32, 1024)
    const float* __restrict__ v,     // (1024)
    float* __restrict__ part)        // (4, MROWS)
{
  extern __shared__ __align__(16) char lds[];   // 131072 = 2 x (A 32K + B 32K)

  int bid = blockIdx.x;                   // 1024 blocks
  int wg = (bid & 7) * 128 + (bid >> 3);  // bijective XCD-chunked swizzle
  int m_idx = wg >> 2, n_idx = wg & 3;    // 4 n-tiles share one A panel per XCD L2
  long row0 = (long)m_idx * 256;
  int o0 = n_idx * 256;
  int b = (int)(row0 >> 11);

  int tid = threadIdx.x;
  int l = tid & 63, w = tid >> 6;         // 8 waves
  int wr = w >> 2, wc = w & 3;            // 2 (M) x 4 (N); per-wave 128 x 64
  int lr = l & 15, lg = l >> 4;
  int sw = lr & 7;                        // ds_read-side 16B-slot XOR
  int scol = ((tid & 7) ^ ((tid >> 3) & 7)) * 8;  // pre-swizzled global col (f16)

  const f16* Ab = Af + row0 * HID;
  const f16* Bb = Wf + (size_t)o0 * HID;

  const char* la0 = lds;
  const char* lb0 = lds + 32768;
  const char* la1 = lds + 65536;
  const char* lb1 = lds + 98304;

  f32x4 acc[8][4];
#pragma unroll
  for (int m = 0; m < 8; ++m)
#pragma unroll
    for (int n = 0; n < 4; ++n) acc[m][n] = (f32x4){0.f, 0.f, 0.f, 0.f};

  f16x8 aF[4][2], bF0[2][2], bF1[2][2];

  // ---- prologue: tile 0 fully (u0-7), tile 1 u0,u1; tile-0 complete w/ 2 in flight
  STG1(0, 0); STG1(1, 0); STG1(2, 0); STG1(3, 0);
  STG1(4, 0); STG1(5, 0); STG1(6, 0); STG1(7, 0);
  STG1(0, 1); STG1(1, 1);
  VMC(2); SCHED0(); BAR();

#pragma unroll 1
  for (int E = 0; E < 16; E += 2) {
    const int LAST = (E == 14);
    // ---- ph1: tile E quad(0,0)
    RD_A(la0, 0); RD_B(lb0, bF0, 0);
    STG1(2, E + 1); STG1(3, E + 1);
    SCHED0(); BAR(); LGKM0(); SCHED0();
    MFMA16(bF0, 0, 0);
    BAR();
    // ---- ph2: quad(0,1)
    RD_B(lb0, bF1, 1);
    STG1(4, E + 1); STG1(5, E + 1);
    SCHED0(); BAR(); LGKM0(); SCHED0();
    MFMA16(bF1, 0, 1);
    BAR();
    // ---- ph3: quad(1,1)
    RD_A(la0, 1);
    STG1(6, E + 1); STG1(7, E + 1);
    SCHED0(); BAR(); LGKM0(); SCHED0();
    MFMA16(bF1, 1, 1);
    BAR();
    // ---- ph4: quad(1,0); vmcnt(2) -> tile E+1 landed (E+2's u0,u1 in flight)
    if (!LAST) { STG1(0, E + 2); STG1(1, E + 2); }
    SCHED0(); BAR(); LGKM0(); SCHED0();
    MFMA16(bF0, 1, 0);
    if (!LAST) { VMC(2); } else { VMC(0); }
    SCHED0(); BAR();
    // ---- ph5: tile E+1 quad(0,0)
    RD_A(la1, 0); RD_B(lb1, bF0, 0);
    if (!LAST) { STG1(2, E + 2); STG1(3, E + 2); }
    SCHED0(); BAR(); LGKM0(); SCHED0();
    MFMA16(bF0, 0, 0);
    BAR();
    // ---- ph6: quad(0,1)
    RD_B(lb1, bF1, 1);
    if (!LAST) { STG1(4, E + 2); STG1(5, E + 2); }
    SCHED0(); BAR(); LGKM0(); SCHED0();
    MFMA16(bF1, 0, 1);
    BAR();
    // ---- ph7: quad(1,1)
    RD_A(la1, 1);
    if (!LAST) { STG1(6, E + 2); STG1(7, E + 2); }
    SCHED0(); BAR(); LGKM0(); SCHED0();
    MFMA16(bF1, 1, 1);
    BAR();
    // ---- ph8: quad(1,0); vmcnt(2) -> tile E+2 landed (E+3's u0,u1 in flight)
    if (!LAST) { STG1(0, E + 3); STG1(1, E + 3); }
    SCHED0(); BAR(); LGKM0(); SCHED0();
    MFMA16(bF0, 1, 0);
    if (!LAST) { VMC(2); SCHED0(); }
    BAR();
  }

  // ---- fused epilogue: tanh(C + hvec) . v reduced over this block's 256 o's
  float hvv[4], vvv[4];
#pragma unroll
  for (int n = 0; n < 4; ++n) {
    int o = o0 + wc * 64 + n * 16 + lr;
    hvv[n] = hvec[b * HID + o];
    vvv[n] = v[o];
  }
  float* scf = (float*)lds;
  __syncthreads();
#pragma unroll
  for (int m = 0; m < 8; ++m) {
#pragma unroll
    for (int r = 0; r < 4; ++r) {
      float s = 0.f;
#pragma unroll
      for (int n = 0; n < 4; ++n)
        s += fast_tanh(acc[m][n][r] + hvv[n]) * vvv[n];
      s += __shfl_xor(s, 1); s += __shfl_xor(s, 2);
      s += __shfl_xor(s, 4); s += __shfl_xor(s, 8);
      if (lr == 0) scf[wc * 256 + wr * 128 + m * 16 + lg * 4 + r] = s;
    }
  }
  __syncthreads();
  if (tid < 256)
    part[(size_t)n_idx * MROWS + row0 + tid] =
        scf[tid] + scf[256 + tid] + scf[512 + tid] + scf[768 + tid];
}

// ---------------------------------------------------------------- kernel 3 (fallback)
__global__ __launch_bounds__(256, 2) void gemm_fb(
    const float* __restrict__ A, const f16* __restrict__ Wf,
    const float* __restrict__ hvec, const float* __restrict__ v,
    float* __restrict__ part)
{
  __shared__ __align__(16) f16 lA[128][32];
  __shared__ __align__(16) f16 lB[128][32];
  __shared__ float sc[128];

  int bid = blockIdx.x;
  int x = bid & 7, j = bid >> 3;
  int m_idx = x * 64 + (j >> 3);
  int n_idx = j & 7;
  long row0 = (long)m_idx * 128;
  int o0 = n_idx * 128;
  int b = (int)(row0 >> 11);

  int tid = threadIdx.x;
  int l = tid & 63, w = tid >> 6;
  int wr = w >> 1, wc = w & 1;
  int lr = l & 15, lg = l >> 4;

  f32x4 acc[4][4];
#pragma unroll
  for (int m = 0; m < 4; ++m)
#pragma unroll
    for (int n = 0; n < 4; ++n) acc[m][n] = (f32x4){0.f, 0.f, 0.f, 0.f};

  const float* Abase = A + row0 * 1024;

  for (int k0 = 0; k0 < 1024; k0 += 32) {
    __syncthreads();
#pragma unroll
    for (int i = 0; i < 2; ++i) {
      int rr = (i * 256 + tid) >> 2;
      const f16* src = Wf + (size_t)(o0 + rr) * HID + k0 + (tid & 3) * 8;
      char* ldsb = (char*)&lB[0][0] + i * 4096 + w * 1024;
      gload_lds16(src, ldsb);
    }
#pragma unroll
    for (int i = 0; i < 4; ++i) {
      int ja = i * 256 + tid;
      int arow = ja >> 3, ac4 = ja & 7;
      f32x4 d = *(const f32x4*)(Abase + (size_t)arow * 1024 + k0 + ac4 * 4);
      f16x4 q = { (f16)d[0], (f16)d[1], (f16)d[2], (f16)d[3] };
      *(f16x4*)&lA[arow][ac4 * 4] = q;
    }
    __syncthreads();
    f16x8 aF[4], bF[4];
#pragma unroll
    for (int m = 0; m < 4; ++m)
      aF[m] = *(const f16x8*)&lA[wr * 64 + m * 16 + lr][lg * 8];
#pragma unroll
    for (int n = 0; n < 4; ++n)
      bF[n] = *(const f16x8*)&lB[wc * 64 + n * 16 + lr][lg * 8];
#pragma unroll
    for (int m = 0; m < 4; ++m)
#pragma unroll
      for (int n = 0; n < 4; ++n)
        acc[m][n] = __builtin_amdgcn_mfma_f32_16x16x32_f16(aF[m], bF[n], acc[m][n], 0, 0, 0);
  }

  float hv[4], vv[4];
#pragma unroll
  for (int n = 0; n < 4; ++n) {
    int o = o0 + wc * 64 + n * 16 + lr;
    hv[n] = hvec[b * HID + o];
    vv[n] = v[o];
  }
  float myv[4][4];
#pragma unroll
  for (int m = 0; m < 4; ++m) {
#pragma unroll
    for (int r = 0; r < 4; ++r) {
      float s = 0.f;
#pragma unroll
      for (int n = 0; n < 4; ++n)
        s += fast_tanh(acc[m][n][r] + hv[n]) * vv[n];
      s += __shfl_xor(s, 1); s += __shfl_xor(s, 2);
      s += __shfl_xor(s, 4); s += __shfl_xor(s, 8);
      myv[m][r] = s;
    }
  }
  if (wc == 0 && lr == 0) {
#pragma unroll
    for (int m = 0; m < 4; ++m)
#pragma unroll
      for (int r = 0; r < 4; ++r)
        sc[wr * 64 + m * 16 + lg * 4 + r] = myv[m][r];
  }
  __syncthreads();
  if (wc == 1 && lr == 0) {
#pragma unroll
    for (int m = 0; m < 4; ++m)
#pragma unroll
      for (int r = 0; r < 4; ++r)
        sc[wr * 64 + m * 16 + lg * 4 + r] += myv[m][r];
  }
  __syncthreads();
  if (tid < 128)
    part[(size_t)n_idx * MROWS + row0 + tid] = sc[tid];
}

// ---------------------------------------------------------------- kernel 4
__global__ void softmax_k(const float* __restrict__ part, float* __restrict__ out,
                          int nsl) {
  int b = blockIdx.x;
  __shared__ float srow[SRC];
  __shared__ float red[8];
  int tid = threadIdx.x;  // 256

  float lmax = -1e30f;
  for (int i = tid; i < SRC; i += 256) {
    float s = 0.f;
    for (int t = 0; t < nsl; ++t)
      s += part[(size_t)t * MROWS + (size_t)b * SRC + i];
    srow[i] = s;
    lmax = fmaxf(lmax, s);
  }
#pragma unroll
  for (int off = 32; off >= 1; off >>= 1)
    lmax = fmaxf(lmax, __shfl_xor(lmax, off));
  if ((tid & 63) == 0) red[tid >> 6] = lmax;
  __syncthreads();
  float bmax = fmaxf(fmaxf(red[0], red[1]), fmaxf(red[2], red[3]));

  float lsum = 0.f;
  for (int i = tid; i < SRC; i += 256) {
    float e = __expf(srow[i] - bmax);
    srow[i] = e;
    lsum += e;
  }
#pragma unroll
  for (int off = 32; off >= 1; off >>= 1)
    lsum += __shfl_xor(lsum, off);
  if ((tid & 63) == 0) red[4 + (tid >> 6)] = lsum;
  __syncthreads();
  float inv = 1.f / (red[4] + red[5] + red[6] + red[7]);
  for (int i = tid; i < SRC; i += 256)
    out[(size_t)b * SRC + i] = srow[i] * inv;
}

// ---------------------------------------------------------------- launch
extern "C" void kernel_launch(void* const* d_in, const int* in_sizes, int n_in,
                              void* d_out, int out_size, void* d_ws, size_t ws_size,
                              hipStream_t stream) {
  const float* hidden = (const float*)d_in[0];
  const float* enc    = (const float*)d_in[1];
  const float* attn_w = (const float*)d_in[2];
  const float* attn_b = (const float*)d_in[3];
  const float* v      = (const float*)d_in[4];
  float* out = (float*)d_out;

  char* ws = (char*)d_ws;
  f16*   Wf   = (f16*)ws;                                     // 2 MB @ 0
  float* hv   = (float*)(ws + (2ull << 20));                  // 128 KB
  float* part = (float*)(ws + (2ull << 20) + (128ull << 10)); // 2 MB (8 slices max)
  f16*   Af   = (f16*)(ws + (8ull << 20));                    // 128 MB

  const size_t WS_NEEDED = (8ull << 20) + (128ull << 20);

  convw_k<<<1024, 256, 0, stream>>>(attn_w, Wf);
  hvec_k <<<128,  256, 0, stream>>>(hidden, attn_w, attn_b, hv);

  if (ws_size >= WS_NEEDED) {
    convA_k<<<32768, 256, 0, stream>>>(enc, Af);
    gemm_f16<<<1024, 512, 131072, stream>>>(Af, Wf, hv, v, part);
    softmax_k<<<NBATCH, 256, 0, stream>>>(part, out, 4);
  } else {
    gemm_fb<<<4096, 256, 0, stream>>>(enc, Wf, hv, v, part);
    softmax_k<<<NBATCH, 256, 0, stream>>>(part, out, 8);
  }
}